// Round 3
// baseline (2168.790 us; speedup 1.0000x reference)
//
#include <hip/hip_runtime.h>
#include <hip/hip_bf16.h>
#include <math.h>

constexpr int NE = 16;            // experts
constexpr int NG = 4;             // groups
constexpr int NSLICE = 4;         // lanes per token (K-split)
constexpr int TOK_PER_WAVE = 16;
constexpr int WAVES = 4;          // waves per block
constexpr int TOK_PER_BLOCK = TOK_PER_WAVE * WAVES;  // 64
constexpr int DC = 32;            // dims per lane per iteration
// per-wave LDS tile: [16 tokens][4 slices * 36 floats + 8 pad = 152]
constexpr int SLICEF = 36;
constexpr int ROWF   = 152;       // 152 mod 32 = 24 -> rows spread across banks

__global__ __launch_bounds__(256, 4)
void router_kernel(const float* __restrict__ x,
                   const float* __restrict__ w1w,
                   const float* __restrict__ w1b,
                   const float* __restrict__ rbias,
                   float* __restrict__ dout,
                   int n_tokens, int dim)
{
    const int tid  = threadIdx.x;
    const int wid  = tid >> 6;
    const int lane = tid & 63;
    const int r    = lane >> 2;          // token row within wave (0..15)
    const int s    = lane & 3;           // dim slice (0..3)
    const int slice_len = dim / NSLICE;  // 1024
    const int nit = slice_len / DC;      // 32

    __shared__ float xs[WAVES][TOK_PER_WAVE][ROWF];

    const long tw0 = (long)blockIdx.x * TOK_PER_BLOCK + wid * TOK_PER_WAVE;
    const float* xw = x + tw0 * (long)dim;

    double acc[NE];
#pragma unroll
    for (int e = 0; e < NE; ++e) acc[e] = 0.0;

    // staging map: load p in 0..7; lane -> (tok, slice, col) with 128B-contiguous
    // segments: tok = p*2 + (lane>>5), sl = (lane>>3)&3, col = (lane&7)*4
    const int ltok = lane >> 5;          // 0..1
    const int lsl  = (lane >> 3) & 3;    // 0..3
    const int lcol = (lane & 7) << 2;    // 0,4,...,28

    float4 st[8];
#pragma unroll
    for (int p = 0; p < 8; ++p)
        st[p] = *(const float4*)(xw + (long)(p * 2 + ltok) * dim
                                 + lsl * slice_len + lcol);

    for (int c = 0; c < nit; ++c) {
        // write staged chunk to this wave's LDS tile (wave-ordered DS, no barrier)
#pragma unroll
        for (int p = 0; p < 8; ++p)
            *(float4*)&xs[wid][p * 2 + ltok][lsl * SLICEF + lcol] = st[p];

        // prefetch next chunk
        if (c + 1 < nit) {
            const float* xb = xw + lsl * slice_len + (c + 1) * DC + lcol;
#pragma unroll
            for (int p = 0; p < 8; ++p)
                st[p] = *(const float4*)(xb + (long)(p * 2 + ltok) * dim);
        }

        // compute: lane handles token r, dims [s*1024 + c*32 .. +32), fp64 FMA
        const float* wch = w1w + s * slice_len + c * DC;
#pragma unroll
        for (int k = 0; k < DC / 4; ++k) {
            float4 xv = *(const float4*)&xs[wid][r][s * SLICEF + k * 4];
            double x0 = (double)xv.x, x1 = (double)xv.y;
            double x2 = (double)xv.z, x3 = (double)xv.w;
#pragma unroll
            for (int e = 0; e < NE; ++e) {
                const float* wr = wch + e * dim + k * 4;
                acc[e] = fma(x0, (double)wr[0], acc[e]);
                acc[e] = fma(x1, (double)wr[1], acc[e]);
                acc[e] = fma(x2, (double)wr[2], acc[e]);
                acc[e] = fma(x3, (double)wr[3], acc[e]);
            }
        }
    }

    // butterfly reduce across the 4 slice-lanes (deterministic order)
#pragma unroll
    for (int e = 0; e < NE; ++e) {
        acc[e] += __shfl_xor(acc[e], 1, 64);
        acc[e] += __shfl_xor(acc[e], 2, 64);
    }

    // ---- epilogue (fp64), redundant across the 4 lanes of each token ----
    double logit[NE];
    double m = -INFINITY;
#pragma unroll
    for (int e = 0; e < NE; ++e) {
        logit[e] = acc[e] + (double)w1b[e];
        m = fmax(m, logit[e]);
    }
    double ssum = 0.0;
    double p[NE];
#pragma unroll
    for (int e = 0; e < NE; ++e) { p[e] = exp(logit[e] - m); ssum += p[e]; }
    double inv = 1.0 / ssum;
    double sc[NE];
#pragma unroll
    for (int e = 0; e < NE; ++e) sc[e] = p[e] * inv + (double)rbias[e];

    double gm[NG];
#pragma unroll
    for (int g = 0; g < NG; ++g) {
        double a = fmax(sc[g * 4 + 0], sc[g * 4 + 1]);
        double b = fmax(sc[g * 4 + 2], sc[g * 4 + 3]);
        gm[g] = fmax(a, b);
    }
    int g1 = 0;
#pragma unroll
    for (int g = 1; g < NG; ++g) if (gm[g] > gm[g1]) g1 = g;
    int g2 = (g1 == 0) ? 1 : 0;
#pragma unroll
    for (int g = 0; g < NG; ++g) if (g != g1 && gm[g] > gm[g2]) g2 = g;

    double v1 = -INFINITY; int i1 = 0;
#pragma unroll
    for (int e = 0; e < NE; ++e) {
        int g = e >> 2;
        bool keep = (g == g1) || (g == g2);
        if (keep && sc[e] > v1) { v1 = sc[e]; i1 = e; }
    }
    double v2 = -INFINITY; int i2 = 0;
#pragma unroll
    for (int e = 0; e < NE; ++e) {
        int g = e >> 2;
        bool keep = ((g == g1) || (g == g2)) && (e != i1);
        if (keep && sc[e] > v2) { v2 = sc[e]; i2 = e; }
    }

    if (s == 0) {
        long t = tw0 + r;
        float2 vv; vv.x = (float)v1; vv.y = (float)v2;
        *(float2*)(dout + t * 2) = vv;
        float2 iv; iv.x = (float)i1; iv.y = (float)i2;
        *(float2*)(dout + (long)n_tokens * 2 + t * 2) = iv;
    }
}

extern "C" void kernel_launch(void* const* d_in, const int* in_sizes, int n_in,
                              void* d_out, int out_size, void* d_ws, size_t ws_size,
                              hipStream_t stream)
{
    const float* x   = (const float*)d_in[0];
    const float* w1w = (const float*)d_in[1];
    const float* w1b = (const float*)d_in[2];
    const float* rb  = (const float*)d_in[3];
    float* out = (float*)d_out;

    const int ne       = in_sizes[2];            // 16
    const int dim      = in_sizes[1] / ne;       // 4096
    const int n_tokens = in_sizes[0] / dim;      // 65536

    dim3 grid(n_tokens / TOK_PER_BLOCK), block(WAVES * 64);
    hipLaunchKernelGGL(router_kernel, grid, block, 0, stream,
                       x, w1w, w1b, rb, out, n_tokens, dim);
}

// Round 4
// 1067.224 us; speedup vs baseline: 2.0322x; 2.0322x over previous
//
#include <hip/hip_runtime.h>
#include <math.h>

constexpr int NE  = 16;   // experts
constexpr int NG  = 4;    // groups
constexpr int NSL = 4;    // dim slices = waves per block
constexpr int TOK = 64;   // tokens per block (one per lane)
constexpr int DC  = 32;   // dims per chunk
// LDS: staging [4 waves][2 bufs][64 tok][32 f] = 65536 B; reduction area aliases it
constexpr size_t LDS_BYTES = (size_t)NSL * 2 * TOK * DC * 4;  // 65536

__device__ __forceinline__ void gload_lds16(const float* g, float* l) {
    __builtin_amdgcn_global_load_lds(
        (const __attribute__((address_space(1))) void*)g,
        (__attribute__((address_space(3))) void*)l, 16, 0, 0);
}

__global__ __launch_bounds__(256)
void w_transpose_kernel(const float* __restrict__ w, double* __restrict__ wt,
                        int dim, int n) {
    int id = blockIdx.x * 256 + threadIdx.x;
    if (id < n) {
        int e = id / dim;
        int k = id - e * dim;
        wt[(size_t)k * NE + e] = (double)w[id];   // [k][e] layout, fp64
    }
}

template <int W64>
__global__ __launch_bounds__(256)
void router_kernel(const float* __restrict__ x,
                   const float* __restrict__ w32,
                   const double* __restrict__ w64,
                   const float* __restrict__ w1b,
                   const float* __restrict__ rbias,
                   float* __restrict__ dout,
                   int n_tokens, int dim)
{
    __shared__ char ldsraw[LDS_BYTES];
    auto xstg = (float (*)[2][TOK][DC])ldsraw;   // [wave][buf][tok][dim]

    const int tid  = threadIdx.x;
    const int wid  = tid >> 6;            // slice index (per wave)
    const int lane = tid & 63;            // token within tile
    const int slice = dim / NSL;          // 1024
    const int nit  = slice / DC;          // 32 chunks
    const long tw0 = (long)blockIdx.x * TOK;
    const float* xs0 = x + tw0 * dim + (long)wid * slice;

    // staging map: instr i covers tokens i*8..i*8+7; lane -> row lrow, swizzled block
    const int lrow  = lane >> 3;                       // 0..7
    const int lblk4 = ((lane & 7) ^ lrow) << 2;        // XOR source pre-swizzle (floats)

    double acc[NE];
#pragma unroll
    for (int e = 0; e < NE; ++e) acc[e] = 0.0;

    // prologue: stage chunk 0 -> buf 0 (LDS dest = uniform base + lane*16, linear)
#pragma unroll
    for (int i = 0; i < 8; ++i)
        gload_lds16(xs0 + (long)(i * 8 + lrow) * dim + lblk4,
                    &xstg[wid][0][i * 8][0]);

    int cur = 0;
    for (int c = 0; c < nit; ++c) {
        if (c + 1 < nit) {
            const float* gb = xs0 + (c + 1) * DC;
#pragma unroll
            for (int i = 0; i < 8; ++i)
                gload_lds16(gb + (long)(i * 8 + lrow) * dim + lblk4,
                            &xstg[wid][cur ^ 1][i * 8][0]);
            asm volatile("s_waitcnt vmcnt(8)" ::: "memory");  // prev chunk landed
        } else {
            asm volatile("s_waitcnt vmcnt(0)" ::: "memory");
        }
        __builtin_amdgcn_sched_barrier(0);

        const float* xrow = &xstg[wid][cur][lane][0];
        const int kb = wid * slice + c * DC;
#pragma unroll
        for (int b = 0; b < 8; ++b) {
            // slot (lane, b ^ (lane&7)) holds global block b  -> k is wave-uniform
            float4 xv = *(const float4*)(xrow + ((b ^ (lane & 7)) << 2));
            double xd0 = (double)xv.x, xd1 = (double)xv.y;
            double xd2 = (double)xv.z, xd3 = (double)xv.w;
            if (W64) {
                const double* wk = w64 + (size_t)(kb + b * 4) * NE;  // uniform -> s_load
#pragma unroll
                for (int e = 0; e < NE; ++e) {
                    acc[e] = fma(xd0, wk[0 * NE + e], acc[e]);
                    acc[e] = fma(xd1, wk[1 * NE + e], acc[e]);
                    acc[e] = fma(xd2, wk[2 * NE + e], acc[e]);
                    acc[e] = fma(xd3, wk[3 * NE + e], acc[e]);
                }
            } else {
                const int kk = kb + b * 4;
#pragma unroll
                for (int e = 0; e < NE; ++e) {
                    const float* wr = w32 + (size_t)e * dim + kk;    // uniform -> s_load
                    acc[e] = fma(xd0, (double)wr[0], acc[e]);
                    acc[e] = fma(xd1, (double)wr[1], acc[e]);
                    acc[e] = fma(xd2, (double)wr[2], acc[e]);
                    acc[e] = fma(xd3, (double)wr[3], acc[e]);
                }
            }
        }
        cur ^= 1;
    }

    // ---- cross-wave (slice) reduction through LDS (aliases staging) ----
    __syncthreads();
    auto red = (double (*)[TOK][NE + 2])ldsraw;   // [4][64][18] = 36864 B
#pragma unroll
    for (int e = 0; e < NE; ++e) red[wid][lane][e] = acc[e];
    __syncthreads();
    if (wid != 0) return;

    double tot[NE];
#pragma unroll
    for (int e = 0; e < NE; ++e)
        tot[e] = ((red[0][lane][e] + red[1][lane][e]) + red[2][lane][e])
                 + red[3][lane][e];

    // ---- fp64 epilogue: softmax + bias + group-limited top-2 ----
    double logit[NE];
    double m = -INFINITY;
#pragma unroll
    for (int e = 0; e < NE; ++e) {
        logit[e] = tot[e] + (double)w1b[e];
        m = fmax(m, logit[e]);
    }
    double ssum = 0.0;
    double p[NE];
#pragma unroll
    for (int e = 0; e < NE; ++e) { p[e] = exp(logit[e] - m); ssum += p[e]; }
    double inv = 1.0 / ssum;
    double sc[NE];
#pragma unroll
    for (int e = 0; e < NE; ++e) sc[e] = p[e] * inv + (double)rbias[e];

    double gm[NG];
#pragma unroll
    for (int g = 0; g < NG; ++g) {
        double a = fmax(sc[g * 4 + 0], sc[g * 4 + 1]);
        double b = fmax(sc[g * 4 + 2], sc[g * 4 + 3]);
        gm[g] = fmax(a, b);
    }
    int g1 = 0;
#pragma unroll
    for (int g = 1; g < NG; ++g) if (gm[g] > gm[g1]) g1 = g;
    int g2 = (g1 == 0) ? 1 : 0;
#pragma unroll
    for (int g = 0; g < NG; ++g) if (g != g1 && gm[g] > gm[g2]) g2 = g;

    double v1 = -INFINITY; int i1 = 0;
#pragma unroll
    for (int e = 0; e < NE; ++e) {
        int g = e >> 2;
        bool keep = (g == g1) || (g == g2);
        if (keep && sc[e] > v1) { v1 = sc[e]; i1 = e; }
    }
    double v2 = -INFINITY; int i2 = 0;
#pragma unroll
    for (int e = 0; e < NE; ++e) {
        int g = e >> 2;
        bool keep = ((g == g1) || (g == g2)) && (e != i1);
        if (keep && sc[e] > v2) { v2 = sc[e]; i2 = e; }
    }

    long t = tw0 + lane;
    float2 vv; vv.x = (float)v1; vv.y = (float)v2;
    *(float2*)(dout + t * 2) = vv;
    float2 iv; iv.x = (float)i1; iv.y = (float)i2;
    *(float2*)(dout + (long)n_tokens * 2 + t * 2) = iv;
}

extern "C" void kernel_launch(void* const* d_in, const int* in_sizes, int n_in,
                              void* d_out, int out_size, void* d_ws, size_t ws_size,
                              hipStream_t stream)
{
    const float* x   = (const float*)d_in[0];
    const float* w1w = (const float*)d_in[1];
    const float* w1b = (const float*)d_in[2];
    const float* rb  = (const float*)d_in[3];
    float* out = (float*)d_out;

    const int ne       = in_sizes[2];            // 16
    const int dim      = in_sizes[1] / ne;       // 4096
    const int n_tokens = in_sizes[0] / dim;      // 65536

    const int nW = dim * ne;                     // 65536 w elements
    const bool use64 = ws_size >= (size_t)nW * sizeof(double);

    dim3 grid(n_tokens / TOK), block(NSL * 64);
    if (use64) {
        double* wt = (double*)d_ws;
        hipLaunchKernelGGL(w_transpose_kernel, dim3((nW + 255) / 256), dim3(256),
                           0, stream, w1w, wt, dim, nW);
        hipLaunchKernelGGL((router_kernel<1>), grid, block, 0, stream,
                           x, w1w, (const double*)wt, w1b, rb, out, n_tokens, dim);
    } else {
        hipLaunchKernelGGL((router_kernel<0>), grid, block, 0, stream,
                           x, w1w, (const double*)nullptr, w1b, rb, out, n_tokens, dim);
    }
}

// Round 5
// 511.241 us; speedup vs baseline: 4.2422x; 2.0875x over previous
//
#include <hip/hip_runtime.h>
#include <math.h>

constexpr int NE  = 16;   // experts
constexpr int NG  = 4;    // groups
constexpr int NSL = 4;    // k-slices = waves per block
constexpr int TOK = 64;   // tokens per block (one per lane)
constexpr int KS  = 16;   // k per iteration (64B line per lane per step)

__global__ __launch_bounds__(256)
void w_transpose_kernel(const float* __restrict__ w, double* __restrict__ wt,
                        int dim, int n) {
    int id = blockIdx.x * 256 + threadIdx.x;
    if (id < n) {
        int e = id / dim;
        int k = id - e * dim;
        wt[(size_t)k * NE + e] = (double)w[id];   // [k][e] fp64
    }
}

template <int W64>
__global__ __launch_bounds__(256)
void router_kernel(const float* __restrict__ x,
                   const float* __restrict__ w32,
                   const double* __restrict__ w64,
                   const float* __restrict__ w1b,
                   const float* __restrict__ rbias,
                   float* __restrict__ dout,
                   int n_tokens, int dim)
{
    const int tid  = threadIdx.x;
    // readfirstlane result is uniform by definition -> w addressing scalarizes
    const int uwid = __builtin_amdgcn_readfirstlane(tid >> 6);
    const int lane = tid & 63;
    const int slice = dim / NSL;          // 1024
    const long t0  = (long)blockIdx.x * TOK;
    const long tok = t0 + lane;

    const float* xp = x + tok * (size_t)dim + (size_t)uwid * slice;

    double acc[NE];
#pragma unroll
    for (int e = 0; e < NE; ++e) acc[e] = 0.0;

    // prefetch first 64B line per lane
    float4 c0 = *(const float4*)(xp + 0);
    float4 c1 = *(const float4*)(xp + 4);
    float4 c2 = *(const float4*)(xp + 8);
    float4 c3 = *(const float4*)(xp + 12);

    for (int k = 0; k < slice; k += KS) {
        float4 n0, n1, n2, n3;
        if (k + KS < slice) {
            const float* xn = xp + k + KS;
            n0 = *(const float4*)(xn + 0);
            n1 = *(const float4*)(xn + 4);
            n2 = *(const float4*)(xn + 8);
            n3 = *(const float4*)(xn + 12);
        } else { n0 = c0; n1 = c1; n2 = c2; n3 = c3; }

        float xs_[KS];
        xs_[0]  = c0.x; xs_[1]  = c0.y; xs_[2]  = c0.z; xs_[3]  = c0.w;
        xs_[4]  = c1.x; xs_[5]  = c1.y; xs_[6]  = c1.z; xs_[7]  = c1.w;
        xs_[8]  = c2.x; xs_[9]  = c2.y; xs_[10] = c2.z; xs_[11] = c2.w;
        xs_[12] = c3.x; xs_[13] = c3.y; xs_[14] = c3.z; xs_[15] = c3.w;

        if (W64) {
            const double* wp = w64 + (size_t)(uwid * slice + k) * NE;  // uniform
#pragma unroll
            for (int kk = 0; kk < KS; ++kk) {
                double xv = (double)xs_[kk];
#pragma unroll
                for (int e = 0; e < NE; ++e)
                    acc[e] = fma(xv, wp[kk * NE + e], acc[e]);
            }
        } else {
            const int kb = uwid * slice + k;                            // uniform
#pragma unroll
            for (int kk = 0; kk < KS; ++kk) {
                double xv = (double)xs_[kk];
#pragma unroll
                for (int e = 0; e < NE; ++e)
                    acc[e] = fma(xv, (double)w32[(size_t)e * dim + kb + kk], acc[e]);
            }
        }
        c0 = n0; c1 = n1; c2 = n2; c3 = n3;
    }

    // ---- cross-wave (slice) reduction: waves 1..3 park partials in LDS ----
    __shared__ double red[NSL - 1][TOK][NE + 1];   // 26112 B
    if (uwid != 0) {
#pragma unroll
        for (int e = 0; e < NE; ++e) red[uwid - 1][lane][e] = acc[e];
    }
    __syncthreads();
    if (uwid != 0) return;

    double tot[NE];
#pragma unroll
    for (int e = 0; e < NE; ++e)
        tot[e] = ((acc[e] + red[0][lane][e]) + red[1][lane][e]) + red[2][lane][e];

    // ---- fp64 epilogue: softmax + bias + group-limited top-2 ----
    double logit[NE];
    double m = -INFINITY;
#pragma unroll
    for (int e = 0; e < NE; ++e) {
        logit[e] = tot[e] + (double)w1b[e];
        m = fmax(m, logit[e]);
    }
    double ssum = 0.0;
    double p[NE];
#pragma unroll
    for (int e = 0; e < NE; ++e) { p[e] = exp(logit[e] - m); ssum += p[e]; }
    double inv = 1.0 / ssum;
    double sc[NE];
#pragma unroll
    for (int e = 0; e < NE; ++e) sc[e] = p[e] * inv + (double)rbias[e];

    double gm[NG];
#pragma unroll
    for (int g = 0; g < NG; ++g) {
        double a = fmax(sc[g * 4 + 0], sc[g * 4 + 1]);
        double b = fmax(sc[g * 4 + 2], sc[g * 4 + 3]);
        gm[g] = fmax(a, b);
    }
    int g1 = 0;
#pragma unroll
    for (int g = 1; g < NG; ++g) if (gm[g] > gm[g1]) g1 = g;
    int g2 = (g1 == 0) ? 1 : 0;
#pragma unroll
    for (int g = 0; g < NG; ++g) if (g != g1 && gm[g] > gm[g2]) g2 = g;

    double v1 = -INFINITY; int i1 = 0;
#pragma unroll
    for (int e = 0; e < NE; ++e) {
        int g = e >> 2;
        bool keep = (g == g1) || (g == g2);
        if (keep && sc[e] > v1) { v1 = sc[e]; i1 = e; }
    }
    double v2 = -INFINITY; int i2 = 0;
#pragma unroll
    for (int e = 0; e < NE; ++e) {
        int g = e >> 2;
        bool keep = ((g == g1) || (g == g2)) && (e != i1);
        if (keep && sc[e] > v2) { v2 = sc[e]; i2 = e; }
    }

    float2 vv; vv.x = (float)v1; vv.y = (float)v2;
    *(float2*)(dout + tok * 2) = vv;
    float2 iv; iv.x = (float)i1; iv.y = (float)i2;
    *(float2*)(dout + (long)n_tokens * 2 + tok * 2) = iv;
}

extern "C" void kernel_launch(void* const* d_in, const int* in_sizes, int n_in,
                              void* d_out, int out_size, void* d_ws, size_t ws_size,
                              hipStream_t stream)
{
    const float* x   = (const float*)d_in[0];
    const float* w1w = (const float*)d_in[1];
    const float* w1b = (const float*)d_in[2];
    const float* rb  = (const float*)d_in[3];
    float* out = (float*)d_out;

    const int ne       = in_sizes[2];            // 16
    const int dim      = in_sizes[1] / ne;       // 4096
    const int n_tokens = in_sizes[0] / dim;      // 65536

    const int nW = dim * ne;                     // 65536 w elements
    const bool use64 = ws_size >= (size_t)nW * sizeof(double);

    dim3 grid(n_tokens / TOK), block(NSL * 64);
    if (use64) {
        double* wt = (double*)d_ws;
        hipLaunchKernelGGL(w_transpose_kernel, dim3((nW + 255) / 256), dim3(256),
                           0, stream, w1w, wt, dim, nW);
        hipLaunchKernelGGL((router_kernel<1>), grid, block, 0, stream,
                           x, w1w, (const double*)wt, w1b, rb, out, n_tokens, dim);
    } else {
        hipLaunchKernelGGL((router_kernel<0>), grid, block, 0, stream,
                           x, w1w, (const double*)nullptr, w1b, rb, out, n_tokens, dim);
    }
}